// Round 8
// baseline (561.216 us; speedup 1.0000x reference)
//
#include <hip/hip_runtime.h>
#include <hip/hip_bf16.h>
#include <stdint.h>

typedef uint32_t u32;
typedef unsigned short u16;
typedef float v2f __attribute__((ext_vector_type(2)));

#define NLAT_I 361
#define NLON_I 720
#define NLAT_O 181
#define NLON_O 360
#define KK 9
#define NNZ 120000
#define NSEG (KK * NLAT_O)            /* 1629 */
#define NPIX (NLAT_O * NLON_O)        /* 65160 */
#define NCH 32
#define SORT_CAP 512
#define ROWLEN 5760                   /* u32 words per (hi,p) row: 360*16 */

/* stage1 persistent geometry: 233 blocks x 7 segs = 1631 >= 1629, all co-resident */
#define NBLK1 233
#define SEGS_PER_BLK 7
#define NC 6                          /* sorted-hi phases (~12 entries/slot/phase) */
#define LDSCAP 160                    /* staged recs per segment (max cnt ~110) */
#define SPIN_LIMIT 100

__device__ __forceinline__ u32 f2bf_rne(float f) {
    u32 b = __float_as_uint(f);
    return (b + 0x7FFFu + ((b >> 16) & 1u)) >> 16;
}

__device__ __forceinline__ int imin(int a, int b) { return a < b ? a : b; }

// ---------------- repack: x[32][361][720] f32 -> xp[hi*2+p][j][cp] bf16x2 ---
__global__ __launch_bounds__(256) void repack_kernel(const float* __restrict__ x,
                                                     u32* __restrict__ xp) {
    __shared__ u16 tile[32][732];
    int hi = blockIdx.x;               // 361 blocks
    int tid = threadIdx.x;
    const size_t plane = (size_t)NLAT_I * NLON_I;
#pragma unroll 1
    for (int c = 0; c < NCH; c++) {
        for (int col = tid; col < NLON_I; col += 256) {
            tile[c][col] = (u16)f2bf_rne(x[c * plane + (size_t)hi * NLON_I + col]);
        }
    }
    __syncthreads();
    for (int wdx = tid; wdx < 2 * ROWLEN; wdx += 256) {
        int p = wdx / ROWLEN;
        int rem = wdx - p * ROWLEN;
        int j = rem >> 4;
        int cp = rem & 15;
        int col = 2 * j + p;
        u32 v = (u32)tile[2 * cp][col] | ((u32)tile[2 * cp + 1][col] << 16);
        xp[(size_t)(2 * hi + p) * ROWLEN + rem] = v;
    }
}

// ---------------- CSR build ------------------------------------------------
__global__ __launch_bounds__(256) void hist_kernel(const int* __restrict__ ker,
                                                   const int* __restrict__ row,
                                                   int* __restrict__ counts) {
    int e = blockIdx.x * 256 + threadIdx.x;
    if (e >= NNZ) return;
    int seg = ker[e] * NLAT_O + row[e];
    atomicAdd(&counts[seg], 1);
}

__global__ __launch_bounds__(256) void scan_kernel(const int* __restrict__ counts,
                                                   int* __restrict__ offsets) {
    __shared__ int lsum[256];
    const int CH = 7;                  // 256*7 = 1792 >= 1629
    int t = threadIdx.x;
    int base = t * CH;
    int local[CH];
    int s = 0;
    for (int i = 0; i < CH; i++) {
        int v = (base + i < NSEG) ? counts[base + i] : 0;
        local[i] = s;
        s += v;
    }
    lsum[t] = s;
    __syncthreads();
    for (int off = 1; off < 256; off <<= 1) {
        int v = 0;
        if (t >= off) v = lsum[t - off];
        __syncthreads();
        if (t >= off) lsum[t] += v;
        __syncthreads();
    }
    int pre = (t == 0) ? 0 : lsum[t - 1];
    for (int i = 0; i < CH; i++) {
        if (base + i < NSEG) offsets[base + i] = pre + local[i];
    }
}

__global__ __launch_bounds__(256) void scatter_kernel(const int* __restrict__ ker,
                                                      const int* __restrict__ row,
                                                      const int* __restrict__ col,
                                                      const float* __restrict__ vals,
                                                      const int* __restrict__ offsets,
                                                      int* __restrict__ cursor,
                                                      int2* __restrict__ recs) {
    int e = blockIdx.x * 256 + threadIdx.x;
    if (e >= NNZ) return;
    int seg = ker[e] * NLAT_O + row[e];
    int pos = offsets[seg] + atomicAdd(&cursor[seg], 1);
    int c  = col[e];
    int hi = c / NLON_I;
    int wi = c % NLON_I;
    int p  = wi & 1;
    int a  = wi >> 1;                  // < 360
    u32 meta = ((u32)hi << 10) | ((u32)p << 9) | (u32)a;
    recs[pos] = make_int2((int)meta, __float_as_int(vals[e]));
}

// ---------------- per-segment sort by meta (hi,p,a ascending) --------------
__global__ __launch_bounds__(256) void sort_kernel(const int* __restrict__ offs,
                                                   const int* __restrict__ cnts,
                                                   int2* __restrict__ recs) {
    __shared__ u32 skey[SORT_CAP];
    __shared__ u32 sval[SORT_CAP];
    int s = blockIdx.x;
    int start = offs[s];
    int cnt = cnts[s];
    if (cnt > SORT_CAP) return;       // perf-only transform; safe to skip
    int t = threadIdx.x;
    for (int i = t; i < cnt; i += 256) {
        int2 r = recs[start + i];
        skey[i] = (u32)r.x;
        sval[i] = (u32)r.y;
    }
    __syncthreads();
    for (int i = t; i < cnt; i += 256) {
        u32 k = skey[i];
        int rank = 0;
        for (int j = 0; j < cnt; j++) {
            u32 kj = skey[j];
            rank += (kj < k || (kj == k && j < i)) ? 1 : 0;
        }
        recs[start + rank] = make_int2((int)k, (int)sval[i]);
    }
}

// ---------------- stage1: persistent, channel-split, phase-synced ----------
// thread = (wo, channel-half). acc = v2f[7][8] (112 f32, lands in AGPR half of
// the unified file). Inner loop: 2-pair-deep ROTATING register pipeline so
// 4-8 dwordx4 stay in flight continuously (no iteration-boundary vmcnt drain).

__device__ __forceinline__ v2f bf2(u32 u) {
    v2f r;
    r.x = __uint_as_float(u << 16);
    r.y = __uint_as_float(u & 0xFFFF0000u);
    return r;
}

__device__ __forceinline__ const uint4* entry_ptr(const u32* __restrict__ xph,
                                                  u32 m, int w) {
    int row = (int)(m >> 9);            // hi*2+p
    int a   = (int)(m & 0x1FF);
    int idx = a + w;
    idx = (idx >= NLON_O) ? idx - NLON_O : idx;
    return (const uint4*)(xph + ((size_t)(row * NLON_O + idx) << 4));
}

#define FMA8(q0, q1, vv, A)                 \
    {                                       \
        A[0] = bf2(q0.x) * vv + A[0];       \
        A[1] = bf2(q0.y) * vv + A[1];       \
        A[2] = bf2(q0.z) * vv + A[2];       \
        A[3] = bf2(q0.w) * vv + A[3];       \
        A[4] = bf2(q1.x) * vv + A[4];       \
        A[5] = bf2(q1.y) * vv + A[5];       \
        A[6] = bf2(q1.z) * vv + A[6];       \
        A[7] = bf2(q1.w) * vv + A[7];       \
    }

// pipeline stage macros (named register sets; all indices static -- rule #20)
#define DECLP(X) uint4 X##q0, X##q1, X##q2, X##q3; v2f X##v0, X##v1;

#define LOADP(X, rec, i)                                        \
    {                                                           \
        int2 r0_ = (rec)[(i)];                                  \
        int2 r1_ = (rec)[(i) + 1];                              \
        float f0_ = __int_as_float(r0_.y);                      \
        float f1_ = __int_as_float(r1_.y);                      \
        X##v0 = (v2f){f0_, f0_};                                \
        X##v1 = (v2f){f1_, f1_};                                \
        const uint4* p0_ = entry_ptr(xph, (u32)r0_.x, w);       \
        const uint4* p1_ = entry_ptr(xph, (u32)r1_.x, w);       \
        X##q0 = p0_[0];                                         \
        X##q1 = p0_[1];                                         \
        X##q2 = p1_[0];                                         \
        X##q3 = p1_[1];                                         \
    }

#define CONSP(X, A)                                             \
    {                                                           \
        FMA8(X##q0, X##q1, X##v0, A)                            \
        FMA8(X##q2, X##q3, X##v1, A)                            \
    }

__device__ __forceinline__ void proc_single(const u32* __restrict__ xph,
                                            const int2* __restrict__ rec,
                                            int i, int w, v2f* __restrict__ A) {
    int2 r0 = rec[i];
    float vf = __int_as_float(r0.y);
    v2f vv = {vf, vf};
    const uint4* p0 = entry_ptr(xph, (u32)r0.x, w);
    uint4 q0 = p0[0];
    uint4 q1 = p0[1];
    FMA8(q0, q1, vv, A)
}

__device__ __forceinline__ void proc_range(const u32* __restrict__ xph,
                                           const int2* __restrict__ rec,
                                           int beg, int end, int w,
                                           v2f* __restrict__ A) {
    int n = end - beg;
    if (n <= 0) return;
    if (n & 1) {                       // peel odd entry
        proc_single(xph, rec, beg, w, A);
        beg++;
        n--;
    }
    if (n <= 0) return;
    DECLP(Pa)
    DECLP(Pb)
    if (n >= 4) {
        LOADP(Pa, rec, beg)
        LOADP(Pb, rec, beg + 2)
        int i = beg + 4;
#pragma unroll 1
        for (; i + 4 <= end; i += 4) {
            CONSP(Pa, A)
            LOADP(Pa, rec, i)
            CONSP(Pb, A)
            LOADP(Pb, rec, i + 2)
        }
        if (i < end) {                 // 2 entries remain
            CONSP(Pa, A)
            LOADP(Pa, rec, i)
            CONSP(Pb, A)
            CONSP(Pa, A)
        } else {
            CONSP(Pa, A)
            CONSP(Pb, A)
        }
    } else {                           // n == 2
        LOADP(Pa, rec, beg)
        CONSP(Pa, A)
    }
}

__global__ __launch_bounds__(768, 3) void stage1_kernel(const u32* __restrict__ xp,
                                                        const int* __restrict__ offs,
                                                        const int* __restrict__ cnts,
                                                        const int2* __restrict__ recs,
                                                        int* __restrict__ ctr,
                                                        u16* __restrict__ xk) {
    __shared__ int2 lrec[SEGS_PER_BLK][LDSCAP];
    __shared__ int scnt[SEGS_PER_BLK], soff[SEGS_PER_BLK];

    int b = blockIdx.x;
    int tid = threadIdx.x;

    if (tid < SEGS_PER_BLK) {
        int s = b * SEGS_PER_BLK + tid;
        int ok = (s < NSEG);
        scnt[tid] = ok ? cnts[s] : 0;
        soff[tid] = ok ? offs[s] : 0;
    }
    __syncthreads();

#pragma unroll
    for (int slot = 0; slot < SEGS_PER_BLK; slot++) {
        int c = imin(scnt[slot], LDSCAP);
        int o = soff[slot];
        for (int i = tid; i < c; i += 768) lrec[slot][i] = recs[o + i];
    }
    __syncthreads();

    int wo = tid >> 1, h = tid & 1;
    bool act = wo < NLON_O;
    int w = act ? wo : 0;
    const u32* xph = xp + h * 8;

    v2f acc[SEGS_PER_BLK][8];
#pragma unroll
    for (int slot = 0; slot < SEGS_PER_BLK; slot++)
#pragma unroll
        for (int j = 0; j < 8; j++) acc[slot][j] = (v2f){0.0f, 0.0f};

    for (int c = 0; c < NC; c++) {
#pragma unroll
        for (int slot = 0; slot < SEGS_PER_BLK; slot++) {
            int cnt = scnt[slot];
            int beg = (c * cnt) / NC;
            int end = ((c + 1) * cnt) / NC;
            if (end <= LDSCAP) {
                proc_range(xph, lrec[slot], beg, end, w, acc[slot]);
            } else {
                proc_range(xph, recs + soff[slot], beg, end, w, acc[slot]);
            }
        }
        if (c < NC - 1) {
            // bounded-spin quasi-barrier: keeps all co-resident blocks on the
            // same sorted-hi chunk (~2.8 MB live xp slice -> per-XCD L2 hot).
            // Deadlock-free: spin capped; correctness never depends on it.
            __syncthreads();
            if (tid == 0) {
                __hip_atomic_fetch_add(&ctr[c], 1, __ATOMIC_RELAXED,
                                       __HIP_MEMORY_SCOPE_AGENT);
                int spins = 0;
                while (spins < SPIN_LIMIT &&
                       __hip_atomic_load(&ctr[c], __ATOMIC_RELAXED,
                                         __HIP_MEMORY_SCOPE_AGENT) < (int)gridDim.x) {
                    __builtin_amdgcn_s_sleep(2);
                    ++spins;
                }
            }
            __syncthreads();
        }
    }

    if (act) {
#pragma unroll
        for (int slot = 0; slot < SEGS_PER_BLK; slot++) {
            int s = b * SEGS_PER_BLK + slot;
            if (s < NSEG) {
                int k = s / NLAT_O;
                int ho = s - k * NLAT_O;
                int pix = ho * NLON_O + wo;
#pragma unroll
                for (int j = 0; j < 8; j++) {
                    int ch = h * 16 + 2 * j;
                    xk[(size_t)(ch * KK + k) * NPIX + pix] =
                        (u16)f2bf_rne(acc[slot][j].x);
                    xk[(size_t)((ch + 1) * KK + k) * NPIX + pix] =
                        (u16)f2bf_rne(acc[slot][j].y);
                }
            }
        }
    }
}

// ---------------- stage2: out[32][65160] = W[32][288] * xk[288][65160] -----
__global__ __launch_bounds__(256) void stage2_kernel(const u16* __restrict__ xk,
                                                     const float* __restrict__ W,
                                                     const float* __restrict__ bias,
                                                     float* __restrict__ out) {
    int t = blockIdx.x * 256 + threadIdx.x;    // pix-pair id
    bool act = t < NPIX / 2;
    int px = act ? t : 0;
    const u32* xk32 = (const u32*)xk;
    float a0[NCH], a1[NCH];
#pragma unroll
    for (int o = 0; o < NCH; o++) { a0[o] = 0.0f; a1[o] = 0.0f; }
#pragma unroll 4
    for (int r = 0; r < NCH * KK; r++) {
        u32 u = xk32[(size_t)r * (NPIX / 2) + px];
        float x0 = __uint_as_float(u << 16);
        float x1 = __uint_as_float(u & 0xFFFF0000u);
#pragma unroll
        for (int o = 0; o < NCH; o++) {
            float wv = W[o * (NCH * KK) + r];
            a0[o] = fmaf(wv, x0, a0[o]);
            a1[o] = fmaf(wv, x1, a1[o]);
        }
    }
    if (act) {
#pragma unroll
        for (int o = 0; o < NCH; o++) {
            float2 v = make_float2(a0[o] + bias[o], a1[o] + bias[o]);
            *(float2*)(out + (size_t)o * NPIX + 2 * t) = v;
        }
    }
}

// ---------------- launch ---------------------------------------------------
extern "C" void kernel_launch(void* const* d_in, const int* in_sizes, int n_in,
                              void* d_out, int out_size, void* d_ws, size_t ws_size,
                              hipStream_t stream) {
    const float* x    = (const float*)d_in[0];
    const int* ker    = (const int*)d_in[1];
    const int* row    = (const int*)d_in[2];
    const int* col    = (const int*)d_in[3];
    const float* vals = (const float*)d_in[4];
    const float* W    = (const float*)d_in[5];
    const float* bias = (const float*)d_in[6];
    float* out        = (float*)d_out;

    char* ws = (char*)d_ws;
    const size_t off_xp   = 0;
    const size_t sz_xp    = (size_t)NLAT_I * 2 * ROWLEN * 4;   // 16,634,880
    const size_t off_cnt  = off_xp + sz_xp;
    const size_t off_off  = off_cnt + 6528;
    const size_t off_cur  = off_off + 6528;
    const size_t off_ctr  = off_cur + 6528;                    // 64 B (NC ints)
    const size_t off_rec  = off_ctr + 64;                      // 8-aligned
    const size_t off_xk   = off_rec + (size_t)NNZ * 8;

    u32* xp      = (u32*)(ws + off_xp);
    int* counts  = (int*)(ws + off_cnt);
    int* offsets = (int*)(ws + off_off);
    int* cursor  = (int*)(ws + off_cur);
    int* ctr     = (int*)(ws + off_ctr);
    int2* recs   = (int2*)(ws + off_rec);
    u16* xk      = (u16*)(ws + off_xk);

    // zero counts + offsets + cursor + barrier counters
    hipMemsetAsync(ws + off_cnt, 0, 3 * 6528 + 64, stream);

    repack_kernel<<<NLAT_I, 256, 0, stream>>>(x, xp);
    hist_kernel<<<(NNZ + 255) / 256, 256, 0, stream>>>(ker, row, counts);
    scan_kernel<<<1, 256, 0, stream>>>(counts, offsets);
    scatter_kernel<<<(NNZ + 255) / 256, 256, 0, stream>>>(ker, row, col, vals,
                                                          offsets, cursor, recs);
    sort_kernel<<<NSEG, 256, 0, stream>>>(offsets, counts, recs);
    stage1_kernel<<<NBLK1, 768, 0, stream>>>(xp, offsets, counts, recs, ctr, xk);
    stage2_kernel<<<(NPIX / 2 + 255) / 256, 256, 0, stream>>>(xk, W, bias, out);
}

// Round 9
// 339.260 us; speedup vs baseline: 1.6542x; 1.6542x over previous
//
#include <hip/hip_runtime.h>
#include <hip/hip_bf16.h>
#include <stdint.h>

typedef uint32_t u32;
typedef unsigned short u16;
typedef float v2f __attribute__((ext_vector_type(2)));

#define NLAT_I 361
#define NLON_I 720
#define NLAT_O 181
#define NLON_O 360
#define KK 9
#define NNZ 120000
#define NSEG (KK * NLAT_O)            /* 1629 */
#define NPIX (NLAT_O * NLON_O)        /* 65160 */
#define NCH 32
#define SORT_CAP 512
#define ROWLEN 5760                   /* u32 words per (hi,p) row: 360*16 */

/* stage1 persistent geometry: 233 blocks x 7 segs = 1631 >= 1629, all co-resident */
#define NBLK1 233
#define SEGS_PER_BLK 7
#define NC 4                          /* sorted-hi phases (4 MB window ~ per-XCD L2) */
#define LDSCAP 160                    /* staged recs per segment (max cnt ~110) */
#define SPIN_LIMIT 100

__device__ __forceinline__ u32 f2bf_rne(float f) {
    u32 b = __float_as_uint(f);
    return (b + 0x7FFFu + ((b >> 16) & 1u)) >> 16;
}

__device__ __forceinline__ int imin(int a, int b) { return a < b ? a : b; }

// ---------------- repack: x[32][361][720] f32 -> xp[hi*2+p][j][cp] bf16x2 ---
__global__ __launch_bounds__(256) void repack_kernel(const float* __restrict__ x,
                                                     u32* __restrict__ xp) {
    __shared__ u16 tile[32][732];
    int hi = blockIdx.x;               // 361 blocks
    int tid = threadIdx.x;
    const size_t plane = (size_t)NLAT_I * NLON_I;
#pragma unroll 1
    for (int c = 0; c < NCH; c++) {
        for (int col = tid; col < NLON_I; col += 256) {
            tile[c][col] = (u16)f2bf_rne(x[c * plane + (size_t)hi * NLON_I + col]);
        }
    }
    __syncthreads();
    for (int wdx = tid; wdx < 2 * ROWLEN; wdx += 256) {
        int p = wdx / ROWLEN;
        int rem = wdx - p * ROWLEN;
        int j = rem >> 4;
        int cp = rem & 15;
        int col = 2 * j + p;
        u32 v = (u32)tile[2 * cp][col] | ((u32)tile[2 * cp + 1][col] << 16);
        xp[(size_t)(2 * hi + p) * ROWLEN + rem] = v;
    }
}

// ---------------- CSR build ------------------------------------------------
__global__ __launch_bounds__(256) void hist_kernel(const int* __restrict__ ker,
                                                   const int* __restrict__ row,
                                                   int* __restrict__ counts) {
    int e = blockIdx.x * 256 + threadIdx.x;
    if (e >= NNZ) return;
    int seg = ker[e] * NLAT_O + row[e];
    atomicAdd(&counts[seg], 1);
}

__global__ __launch_bounds__(256) void scan_kernel(const int* __restrict__ counts,
                                                   int* __restrict__ offsets) {
    __shared__ int lsum[256];
    const int CH = 7;                  // 256*7 = 1792 >= 1629
    int t = threadIdx.x;
    int base = t * CH;
    int local[CH];
    int s = 0;
    for (int i = 0; i < CH; i++) {
        int v = (base + i < NSEG) ? counts[base + i] : 0;
        local[i] = s;
        s += v;
    }
    lsum[t] = s;
    __syncthreads();
    for (int off = 1; off < 256; off <<= 1) {
        int v = 0;
        if (t >= off) v = lsum[t - off];
        __syncthreads();
        if (t >= off) lsum[t] += v;
        __syncthreads();
    }
    int pre = (t == 0) ? 0 : lsum[t - 1];
    for (int i = 0; i < CH; i++) {
        if (base + i < NSEG) offsets[base + i] = pre + local[i];
    }
}

__global__ __launch_bounds__(256) void scatter_kernel(const int* __restrict__ ker,
                                                      const int* __restrict__ row,
                                                      const int* __restrict__ col,
                                                      const float* __restrict__ vals,
                                                      const int* __restrict__ offsets,
                                                      int* __restrict__ cursor,
                                                      int2* __restrict__ recs) {
    int e = blockIdx.x * 256 + threadIdx.x;
    if (e >= NNZ) return;
    int seg = ker[e] * NLAT_O + row[e];
    int pos = offsets[seg] + atomicAdd(&cursor[seg], 1);
    int c  = col[e];
    int hi = c / NLON_I;
    int wi = c % NLON_I;
    int p  = wi & 1;
    int a  = wi >> 1;                  // < 360
    u32 meta = ((u32)hi << 10) | ((u32)p << 9) | (u32)a;
    recs[pos] = make_int2((int)meta, __float_as_int(vals[e]));
}

// ---------------- per-segment sort by meta (hi,p,a ascending) --------------
__global__ __launch_bounds__(256) void sort_kernel(const int* __restrict__ offs,
                                                   const int* __restrict__ cnts,
                                                   int2* __restrict__ recs) {
    __shared__ u32 skey[SORT_CAP];
    __shared__ u32 sval[SORT_CAP];
    int s = blockIdx.x;
    int start = offs[s];
    int cnt = cnts[s];
    if (cnt > SORT_CAP) return;       // perf-only transform; safe to skip
    int t = threadIdx.x;
    for (int i = t; i < cnt; i += 256) {
        int2 r = recs[start + i];
        skey[i] = (u32)r.x;
        sval[i] = (u32)r.y;
    }
    __syncthreads();
    for (int i = t; i < cnt; i += 256) {
        u32 k = skey[i];
        int rank = 0;
        for (int j = 0; j < cnt; j++) {
            u32 kj = skey[j];
            rank += (kj < k || (kj == k && j < i)) ? 1 : 0;
        }
        recs[start + rank] = make_int2((int)k, (int)sval[i]);
    }
}

// ---------------- stage1: persistent, channel-split, phase-synced ----------
// thread = (wo, channel-half). acc = v2f[7][8] (112 f32). Inner loop: burst
// unroll-4 (8 independent dwordx4 in flight). This exact structure measured
// 268 us / no spill (r5); rotating-pipeline and LDS-ring variants both
// regressed (spill / bank+barrier costs) -- do not reintroduce without
// freeing registers first.

__device__ __forceinline__ v2f bf2(u32 u) {
    v2f r;
    r.x = __uint_as_float(u << 16);
    r.y = __uint_as_float(u & 0xFFFF0000u);
    return r;
}

__device__ __forceinline__ const uint4* entry_ptr(const u32* __restrict__ xph,
                                                  u32 m, int w) {
    int row = (int)(m >> 9);            // hi*2+p
    int a   = (int)(m & 0x1FF);
    int idx = a + w;
    idx = (idx >= NLON_O) ? idx - NLON_O : idx;
    return (const uint4*)(xph + ((size_t)(row * NLON_O + idx) << 4));
}

#define FMA8(q0, q1, vv, A)                 \
    {                                       \
        A[0] = bf2(q0.x) * vv + A[0];       \
        A[1] = bf2(q0.y) * vv + A[1];       \
        A[2] = bf2(q0.z) * vv + A[2];       \
        A[3] = bf2(q0.w) * vv + A[3];       \
        A[4] = bf2(q1.x) * vv + A[4];       \
        A[5] = bf2(q1.y) * vv + A[5];       \
        A[6] = bf2(q1.z) * vv + A[6];       \
        A[7] = bf2(q1.w) * vv + A[7];       \
    }

__device__ __forceinline__ void proc_range(const u32* __restrict__ xph,
                                           const int2* __restrict__ rec,
                                           int beg, int end, int w,
                                           v2f* __restrict__ A) {
    int i = beg;
#pragma unroll 1
    for (; i + 4 <= end; i += 4) {
        int2 r0 = rec[i];
        int2 r1 = rec[i + 1];
        int2 r2 = rec[i + 2];
        int2 r3 = rec[i + 3];
        const uint4* p0 = entry_ptr(xph, (u32)r0.x, w);
        const uint4* p1 = entry_ptr(xph, (u32)r1.x, w);
        const uint4* p2 = entry_ptr(xph, (u32)r2.x, w);
        const uint4* p3 = entry_ptr(xph, (u32)r3.x, w);
        uint4 a0 = p0[0]; uint4 a1 = p0[1];
        uint4 b0 = p1[0]; uint4 b1 = p1[1];
        uint4 c0 = p2[0]; uint4 c1 = p2[1];
        uint4 d0 = p3[0]; uint4 d1 = p3[1];
        v2f v0 = {__int_as_float(r0.y), __int_as_float(r0.y)};
        v2f v1 = {__int_as_float(r1.y), __int_as_float(r1.y)};
        v2f v2 = {__int_as_float(r2.y), __int_as_float(r2.y)};
        v2f v3 = {__int_as_float(r3.y), __int_as_float(r3.y)};
        FMA8(a0, a1, v0, A)
        FMA8(b0, b1, v1, A)
        FMA8(c0, c1, v2, A)
        FMA8(d0, d1, v3, A)
    }
#pragma unroll 1
    for (; i < end; ++i) {
        int2 r0 = rec[i];
        const uint4* p0 = entry_ptr(xph, (u32)r0.x, w);
        uint4 a0 = p0[0]; uint4 a1 = p0[1];
        v2f v0 = {__int_as_float(r0.y), __int_as_float(r0.y)};
        FMA8(a0, a1, v0, A)
    }
}

__global__ __launch_bounds__(768, 3) void stage1_kernel(const u32* __restrict__ xp,
                                                        const int* __restrict__ offs,
                                                        const int* __restrict__ cnts,
                                                        const int2* __restrict__ recs,
                                                        int* __restrict__ ctr,
                                                        u16* __restrict__ xk) {
    __shared__ int2 lrec[SEGS_PER_BLK][LDSCAP];
    __shared__ int scnt[SEGS_PER_BLK], soff[SEGS_PER_BLK];

    int b = blockIdx.x;
    int tid = threadIdx.x;

    if (tid < SEGS_PER_BLK) {
        int s = b * SEGS_PER_BLK + tid;
        int ok = (s < NSEG);
        scnt[tid] = ok ? cnts[s] : 0;
        soff[tid] = ok ? offs[s] : 0;
    }
    __syncthreads();

#pragma unroll
    for (int slot = 0; slot < SEGS_PER_BLK; slot++) {
        int c = imin(scnt[slot], LDSCAP);
        int o = soff[slot];
        for (int i = tid; i < c; i += 768) lrec[slot][i] = recs[o + i];
    }
    __syncthreads();

    int wo = tid >> 1, h = tid & 1;
    bool act = wo < NLON_O;
    int w = act ? wo : 0;
    const u32* xph = xp + h * 8;

    v2f acc[SEGS_PER_BLK][8];
#pragma unroll
    for (int slot = 0; slot < SEGS_PER_BLK; slot++)
#pragma unroll
        for (int j = 0; j < 8; j++) acc[slot][j] = (v2f){0.0f, 0.0f};

    for (int c = 0; c < NC; c++) {
#pragma unroll
        for (int slot = 0; slot < SEGS_PER_BLK; slot++) {
            int cnt = scnt[slot];
            int beg = (c * cnt) / NC;
            int end = ((c + 1) * cnt) / NC;
            if (end <= LDSCAP) {
                proc_range(xph, lrec[slot], beg, end, w, acc[slot]);
            } else {
                proc_range(xph, recs + soff[slot], beg, end, w, acc[slot]);
            }
        }
        if (c < NC - 1) {
            // bounded-spin quasi-barrier: keeps all co-resident blocks on the
            // same sorted-hi chunk (~4 MB live xp slice -> per-XCD L2 hot).
            // Deadlock-free: spin capped; correctness never depends on it.
            __syncthreads();
            if (tid == 0) {
                __hip_atomic_fetch_add(&ctr[c], 1, __ATOMIC_RELAXED,
                                       __HIP_MEMORY_SCOPE_AGENT);
                int spins = 0;
                while (spins < SPIN_LIMIT &&
                       __hip_atomic_load(&ctr[c], __ATOMIC_RELAXED,
                                         __HIP_MEMORY_SCOPE_AGENT) < (int)gridDim.x) {
                    __builtin_amdgcn_s_sleep(2);
                    ++spins;
                }
            }
            __syncthreads();
        }
    }

    if (act) {
#pragma unroll
        for (int slot = 0; slot < SEGS_PER_BLK; slot++) {
            int s = b * SEGS_PER_BLK + slot;
            if (s < NSEG) {
                int k = s / NLAT_O;
                int ho = s - k * NLAT_O;
                int pix = ho * NLON_O + wo;
#pragma unroll
                for (int j = 0; j < 8; j++) {
                    int ch = h * 16 + 2 * j;
                    xk[(size_t)(ch * KK + k) * NPIX + pix] =
                        (u16)f2bf_rne(acc[slot][j].x);
                    xk[(size_t)((ch + 1) * KK + k) * NPIX + pix] =
                        (u16)f2bf_rne(acc[slot][j].y);
                }
            }
        }
    }
}

// ---------------- stage2: out[32][65160] = W[32][288] * xk[288][65160] -----
// K-split x4: block = 64 pix-pairs x 4 K-slices (72 r each), LDS reduce.
// Old version ran only 128 blocks (2 waves/CU) with a 288-deep serial load
// chain; this one runs 510 blocks and 4x shorter chains.
#define S2_PP 64
#define S2_RPK 72                     /* 288 / 4 */

__global__ __launch_bounds__(256) void stage2_kernel(const u16* __restrict__ xk,
                                                     const float* __restrict__ W,
                                                     const float* __restrict__ bias,
                                                     float* __restrict__ out) {
    __shared__ float2 red[4][S2_PP][17];   // 4*64*17*8 = 34816 B
    int pp  = threadIdx.x & 63;
    int ksl = threadIdx.x >> 6;            // 0..3
    int px2 = blockIdx.x * S2_PP + pp;     // pix-pair id
    bool act = px2 < NPIX / 2;
    int px = act ? px2 : 0;
    const u32* xk32 = (const u32*)xk;

    float a0[NCH], a1[NCH];
#pragma unroll
    for (int o = 0; o < NCH; o++) { a0[o] = 0.0f; a1[o] = 0.0f; }

    int rbase = ksl * S2_RPK;
#pragma unroll 4
    for (int rr = 0; rr < S2_RPK; rr++) {
        int r = rbase + rr;
        u32 u = xk32[(size_t)r * (NPIX / 2) + px];
        float x0 = __uint_as_float(u << 16);
        float x1 = __uint_as_float(u & 0xFFFF0000u);
#pragma unroll
        for (int o = 0; o < NCH; o++) {
            float wv = W[o * (NCH * KK) + r];
            a0[o] = fmaf(wv, x0, a0[o]);
            a1[o] = fmaf(wv, x1, a1[o]);
        }
    }

    // reduce the 4 K-slices via LDS, in 2 half-passes of 16 outputs each
#pragma unroll 1
    for (int half = 0; half < 2; half++) {
        __syncthreads();
#pragma unroll
        for (int j = 0; j < 16; j++) {
            int o = half * 16 + j;
            red[ksl][pp][j] = make_float2(a0[o], a1[o]);
        }
        __syncthreads();
        // wave ksl now handles outputs [ksl*4, ksl*4+4) of this half
#pragma unroll
        for (int j = 0; j < 4; j++) {
            int oo = ksl * 4 + j;
            float2 s0 = red[0][pp][oo];
            float2 s1 = red[1][pp][oo];
            float2 s2 = red[2][pp][oo];
            float2 s3 = red[3][pp][oo];
            float sx = s0.x + s1.x + s2.x + s3.x;
            float sy = s0.y + s1.y + s2.y + s3.y;
            int o = half * 16 + oo;
            if (act) {
                float bv = bias[o];
                float2 v = make_float2(sx + bv, sy + bv);
                *(float2*)(out + (size_t)o * NPIX + 2 * px2) = v;
            }
        }
    }
}

// ---------------- launch ---------------------------------------------------
extern "C" void kernel_launch(void* const* d_in, const int* in_sizes, int n_in,
                              void* d_out, int out_size, void* d_ws, size_t ws_size,
                              hipStream_t stream) {
    const float* x    = (const float*)d_in[0];
    const int* ker    = (const int*)d_in[1];
    const int* row    = (const int*)d_in[2];
    const int* col    = (const int*)d_in[3];
    const float* vals = (const float*)d_in[4];
    const float* W    = (const float*)d_in[5];
    const float* bias = (const float*)d_in[6];
    float* out        = (float*)d_out;

    char* ws = (char*)d_ws;
    const size_t off_xp   = 0;
    const size_t sz_xp    = (size_t)NLAT_I * 2 * ROWLEN * 4;   // 16,634,880
    const size_t off_cnt  = off_xp + sz_xp;
    const size_t off_off  = off_cnt + 6528;
    const size_t off_cur  = off_off + 6528;
    const size_t off_ctr  = off_cur + 6528;                    // 64 B (NC ints)
    const size_t off_rec  = off_ctr + 64;                      // 8-aligned
    const size_t off_xk   = off_rec + (size_t)NNZ * 8;

    u32* xp      = (u32*)(ws + off_xp);
    int* counts  = (int*)(ws + off_cnt);
    int* offsets = (int*)(ws + off_off);
    int* cursor  = (int*)(ws + off_cur);
    int* ctr     = (int*)(ws + off_ctr);
    int2* recs   = (int2*)(ws + off_rec);
    u16* xk      = (u16*)(ws + off_xk);

    // zero counts + offsets + cursor + barrier counters
    hipMemsetAsync(ws + off_cnt, 0, 3 * 6528 + 64, stream);

    repack_kernel<<<NLAT_I, 256, 0, stream>>>(x, xp);
    hist_kernel<<<(NNZ + 255) / 256, 256, 0, stream>>>(ker, row, counts);
    scan_kernel<<<1, 256, 0, stream>>>(counts, offsets);
    scatter_kernel<<<(NNZ + 255) / 256, 256, 0, stream>>>(ker, row, col, vals,
                                                          offsets, cursor, recs);
    sort_kernel<<<NSEG, 256, 0, stream>>>(offsets, counts, recs);
    stage1_kernel<<<NBLK1, 768, 0, stream>>>(xp, offsets, counts, recs, ctr, xk);
    stage2_kernel<<<(NPIX / 2 + S2_PP - 1) / S2_PP, 256, 0, stream>>>(xk, W, bias, out);
}